// Round 6
// baseline (404.623 us; speedup 1.0000x reference)
//
#include <hip/hip_runtime.h>
#include <math.h>

#define BATCH 16
#define CDIM 256
#define HW 9216
#define RDIM 32
#define SPLITS 16
#define KSLAB (HW / SPLITS)   /* 576 */
#define KCH 32                /* gram k-columns per chunk */
#define NCH (KSLAB / KCH)     /* 18 */

#define BN 256                /* out_kernel n-tile */
#define BK 64                 /* out_kernel k-chunk */
#define BOFF 32768            /* ldsB byte offset inside shared block */

typedef __attribute__((ext_vector_type(8))) short short8;
typedef __attribute__((ext_vector_type(4))) short short4_t;
typedef __attribute__((ext_vector_type(4))) float f32x4;

__device__ __forceinline__ unsigned short bf16_rne(float x) {
    union { float f; unsigned u; } a; a.f = x;
    return (unsigned short)((a.u + 0x7fffu + ((a.u >> 16) & 1u)) >> 16);
}
__device__ __forceinline__ float bf16_to_f(unsigned short h) {
    union { unsigned u; float f; } a; a.u = ((unsigned)h) << 16;
    return a.f;
}
__device__ __forceinline__ unsigned pack2(float lo, float hi) {
    return (unsigned)bf16_rne(lo) | ((unsigned)bf16_rne(hi) << 16);
}

// gram swizzle for [256 rows][32 k] bf16 tile (row stride 64 B).
// s(row) = (row ^ (row>>2)) & 3 into byte bits 4-5: b128 frag reads 2-way max
// (free), b64 staging writes conflict-free. Returns SHORT index.
__device__ __forceinline__ int gswz(int row, int k) {
    int byte = (row << 6) + (k << 1);
    byte ^= ((row ^ (row >> 2)) & 3) << 4;
    return byte >> 1;
}
// out-kernel swizzle (unchanged, row stride 128 B)
__device__ __forceinline__ int bofs(int row, int k) {
    return (((row) << 7) | ((k) << 1)) ^ (((row ^ (row >> 2)) & 7) << 4);
}

// ---------------- K1: energy = v v^T (split-K, bf16 hi/lo MFMA) ----------
// 8-wave blocks (2x4 wave grid), block tile 128x256, 2 blocks/CU for
// cross-block phase overlap. Single 32KB LDS tile (all 256 rows x 32 k),
// staged by 512 threads; A-frags read the block's 128-row half, B-frags all
// 256 rows from the SAME tile. Atomic fp32 epilogue.
__global__ __launch_bounds__(512, 4) void gram_kernel(const float* __restrict__ x,
                                                      float* __restrict__ energy,
                                                      float* __restrict__ pooled) {
    int sx    = blockIdx.x;        // split*2 + half
    int split = sx >> 1;
    int half  = sx & 1;
    int b     = blockIdx.y;
    const float* v = x + (size_t)b * CDIM * HW;
    int kbase0 = split * KSLAB;

    __shared__ short ldsH[CDIM * KCH];   // 16 KB
    __shared__ short ldsL[CDIM * KCH];   // 16 KB

    int t    = threadIdx.x;
    int lane = t & 63;
    int wave = t >> 6;             // 0..7
    int wr   = wave >> 2;          // 0..1
    int wc   = wave & 3;           // 0..3
    int lhi  = lane >> 4, llo = lane & 15;
    int srow = t >> 3;             // staging base row 0..63
    int sk   = (t & 7) * 4;        // staging k offset (floats)

    f32x4 acc[4][4];
    #pragma unroll
    for (int i = 0; i < 4; ++i)
        #pragma unroll
        for (int j = 0; j < 4; ++j)
            acc[i][j] = (f32x4){0.f, 0.f, 0.f, 0.f};

    float psum[4] = {0.f, 0.f, 0.f, 0.f};
    float4 f[4];

    // preload chunk 0: thread stages rows srow+64p, floats sk..sk+3
    #pragma unroll
    for (int p = 0; p < 4; ++p)
        f[p] = *(const float4*)&v[(size_t)(srow + 64 * p) * HW + kbase0 + sk];

    for (int ch = 0; ch < NCH; ++ch) {
        // ---- convert (consumes loads; overlaps other block's MFMAs) ----
        short4_t h4[4], l4[4];
        #pragma unroll
        for (int p = 0; p < 4; ++p) {
            psum[p] += f[p].x + f[p].y + f[p].z + f[p].w;
            float vals[4] = { f[p].x, f[p].y, f[p].z, f[p].w };
            #pragma unroll
            for (int j = 0; j < 4; ++j) {
                unsigned short h = bf16_rne(vals[j]);
                float rem = vals[j] - bf16_to_f(h);
                h4[p][j] = (short)h;
                l4[p][j] = (short)bf16_rne(rem);
            }
        }
        __syncthreads();   // (A) prior chunk's frag reads complete
        #pragma unroll
        for (int p = 0; p < 4; ++p) {
            int idx = gswz(srow + 64 * p, sk);
            *(short4_t*)&ldsH[idx] = h4[p];
            *(short4_t*)&ldsL[idx] = l4[p];
        }
        __syncthreads();   // (B) tile staged

        // ---- frag reads ----
        short8 Ah[4], Al[4], Bh[4], Bl[4];
        #pragma unroll
        for (int rb = 0; rb < 4; ++rb) {
            int idx = gswz(half * 128 + wr * 64 + rb * 16 + llo, lhi * 8);
            Ah[rb] = *(const short8*)&ldsH[idx];
            Al[rb] = *(const short8*)&ldsL[idx];
        }
        #pragma unroll
        for (int cb = 0; cb < 4; ++cb) {
            int idx = gswz(wc * 64 + cb * 16 + llo, lhi * 8);
            Bh[cb] = *(const short8*)&ldsH[idx];
            Bl[cb] = *(const short8*)&ldsL[idx];
        }

        // ---- issue next chunk's loads (drain under MFMA window) ----
        if (ch + 1 < NCH) {
            int kb = kbase0 + (ch + 1) * KCH;
            #pragma unroll
            for (int p = 0; p < 4; ++p)
                f[p] = *(const float4*)&v[(size_t)(srow + 64 * p) * HW + kb + sk];
        }

        // ---- MFMA: 16 tiles x (hh + hl + lh) ----
        __builtin_amdgcn_s_setprio(1);
        #pragma unroll
        for (int rb = 0; rb < 4; ++rb)
            #pragma unroll
            for (int cb = 0; cb < 4; ++cb) {
                acc[rb][cb] = __builtin_amdgcn_mfma_f32_16x16x32_bf16(Ah[rb], Bh[cb], acc[rb][cb], 0, 0, 0);
                acc[rb][cb] = __builtin_amdgcn_mfma_f32_16x16x32_bf16(Ah[rb], Bl[cb], acc[rb][cb], 0, 0, 0);
                acc[rb][cb] = __builtin_amdgcn_mfma_f32_16x16x32_bf16(Al[rb], Bh[cb], acc[rb][cb], 0, 0, 0);
            }
        __builtin_amdgcn_s_setprio(0);
    }

    // ---- pooled: register-accumulated, one atomic per (row-slot); half 0 only
    if (half == 0) {
        #pragma unroll
        for (int p = 0; p < 4; ++p) {
            float s = psum[p];
            s += __shfl_xor(s, 1);
            s += __shfl_xor(s, 2);
            s += __shfl_xor(s, 4);
            if ((t & 7) == 0) atomicAdd(&pooled[b * CDIM + srow + 64 * p], s);
        }
    }

    // ---- energy atomic epilogue ----
    #pragma unroll
    for (int rb = 0; rb < 4; ++rb) {
        int r0 = half * 128 + wr * 64 + rb * 16 + lhi * 4;
        #pragma unroll
        for (int cb = 0; cb < 4; ++cb) {
            int c0 = wc * 64 + cb * 16 + llo;
            #pragma unroll
            for (int reg = 0; reg < 4; ++reg)
                atomicAdd(&energy[((size_t)b * CDIM + r0 + reg) * CDIM + c0], acc[rb][cb][reg]);
        }
    }
}

// ---------------- K2: SE MLP -> sigmoid gate ----------------
__global__ __launch_bounds__(256) void se_kernel(const float* __restrict__ pooled,
                                                 const float* __restrict__ w1,
                                                 const float* __restrict__ b1,
                                                 const float* __restrict__ w2,
                                                 const float* __restrict__ b2,
                                                 float* __restrict__ gate) {
    int b = blockIdx.x;
    int t = threadIdx.x;
    __shared__ float p[CDIM];
    __shared__ float hid[RDIM];
    p[t] = pooled[b * CDIM + t] * (1.0f / HW);
    __syncthreads();
    if (t < RDIM) {
        float s = b1[t];
        const float* wr = w1 + t * CDIM;
        for (int k = 0; k < CDIM; ++k) s = fmaf(wr[k], p[k], s);
        hid[t] = s > 0.f ? s : 0.f;
    }
    __syncthreads();
    float s = b2[t];
    const float* wr = w2 + t * RDIM;
    #pragma unroll
    for (int k = 0; k < RDIM; ++k) s = fmaf(wr[k], hid[k], s);
    gate[b * CDIM + t] = 1.0f / (1.0f + expf(-s));
}

// ---------------- K3: row softmax of (rowmax - energy), in place ----------------
__global__ __launch_bounds__(256) void softmax_kernel(float* __restrict__ energy) {
    int row = blockIdx.x;
    float* e = energy + (size_t)row * CDIM;
    int t = threadIdx.x;
    float val = e[t];

    float m = val;
    for (int off = 32; off > 0; off >>= 1) m = fminf(m, __shfl_down(m, off));
    __shared__ float redm[4];
    if ((t & 63) == 0) redm[t >> 6] = m;
    __syncthreads();
    float rowmin = fminf(fminf(redm[0], redm[1]), fminf(redm[2], redm[3]));

    float p = expf(rowmin - val);
    float s = p;
    for (int off = 32; off > 0; off >>= 1) s += __shfl_down(s, off);
    __shared__ float reds[4];
    if ((t & 63) == 0) reds[t >> 6] = s;
    __syncthreads();
    float tot = reds[0] + reds[1] + reds[2] + reds[3];
    e[t] = p / tot;
}

// ---------------- K4: out = gamma * gate * (att @ v) + x  (bf16 MFMA) ----------
__global__ __launch_bounds__(1024) void out_kernel(const float* __restrict__ att,
                                                   const float* __restrict__ x,
                                                   const float* __restrict__ gate,
                                                   const float* __restrict__ gammap,
                                                   float* __restrict__ out) {
    __shared__ __align__(16) char lds[65536];   // A: 32KB @0, B: 32KB @BOFF

    const int t    = threadIdx.x;
    const int lane = t & 63;
    const int wave = t >> 6;
    const int wr   = wave >> 2, wc = wave & 3;
    const int lhi  = lane >> 4, llo = lane & 15;
    const int nblk = blockIdx.x * BN;
    const int b    = blockIdx.y;

    const float* v    = x   + (size_t)b * CDIM * HW;
    const float* attb = att + (size_t)b * CDIM * CDIM;

    f32x4 acc[4][4];
    #pragma unroll
    for (int i = 0; i < 4; ++i)
        #pragma unroll
        for (int j = 0; j < 4; ++j)
            acc[i][j] = (f32x4){0.f, 0.f, 0.f, 0.f};

    float4 va0[2], va1[2], aa[4];

    auto load_chunk = [&](int k0) {
        #pragma unroll
        for (int i = 0; i < 2; ++i) {
            int dd0 = 2 * (wave + 16 * i);
            const float* r0 = v + (size_t)(k0 + dd0) * HW + nblk + lane * 4;
            va0[i] = *(const float4*)r0;
            va1[i] = *(const float4*)(r0 + HW);
        }
        #pragma unroll
        for (int i = 0; i < 4; ++i) {
            int c = (t >> 4) + 64 * i;
            aa[i] = *(const float4*)&attb[(size_t)c * CDIM + k0 + (t & 15) * 4];
        }
    };

    load_chunk(0);

    for (int ch = 0; ch < 4; ++ch) {
        __syncthreads();
        #pragma unroll
        for (int i = 0; i < 2; ++i) {
            int dd0 = 2 * (wave + 16 * i);
            const float* f0 = (const float*)&va0[i];
            const float* f1 = (const float*)&va1[i];
            #pragma unroll
            for (int j = 0; j < 4; ++j) {
                int n = lane * 4 + j;
                *(unsigned*)(lds + BOFF + bofs(n, dd0)) = pack2(f0[j], f1[j]);
            }
        }
        #pragma unroll
        for (int i = 0; i < 4; ++i) {
            int c = (t >> 4) + 64 * i;
            const float* fa = (const float*)&aa[i];
            short4_t h = { (short)bf16_rne(fa[0]), (short)bf16_rne(fa[1]),
                           (short)bf16_rne(fa[2]), (short)bf16_rne(fa[3]) };
            *(short4_t*)(lds + bofs(c, (t & 15) * 4)) = h;
        }
        __syncthreads();

        if (ch < 3) load_chunk((ch + 1) * BK);

        #pragma unroll
        for (int ks = 0; ks < 2; ++ks) {
            int kb = ks * 32 + lhi * 8;
            short8 Af[4], Bf[4];
            #pragma unroll
            for (int rb = 0; rb < 4; ++rb)
                Af[rb] = *(const short8*)(lds + bofs(wr * 64 + rb * 16 + llo, kb));
            #pragma unroll
            for (int cb = 0; cb < 4; ++cb)
                Bf[cb] = *(const short8*)(lds + BOFF + bofs(wc * 64 + cb * 16 + llo, kb));
            #pragma unroll
            for (int rb = 0; rb < 4; ++rb)
                #pragma unroll
                for (int cb = 0; cb < 4; ++cb)
                    acc[rb][cb] = __builtin_amdgcn_mfma_f32_16x16x32_bf16(Af[rb], Bf[cb], acc[rb][cb], 0, 0, 0);
        }
    }

    float gm = gammap[0];
    #pragma unroll
    for (int rb = 0; rb < 4; ++rb) {
        #pragma unroll
        for (int r = 0; r < 4; ++r) {
            int c = wr * 64 + rb * 16 + lhi * 4 + r;
            float g = gm * gate[b * CDIM + c];
            size_t rowbase = ((size_t)b * CDIM + c) * HW + nblk;
            #pragma unroll
            for (int cb = 0; cb < 4; ++cb) {
                int n = wc * 64 + cb * 16 + llo;
                out[rowbase + n] = fmaf(acc[rb][cb][r], g, x[rowbase + n]);
            }
        }
    }
}

extern "C" void kernel_launch(void* const* d_in, const int* in_sizes, int n_in,
                              void* d_out, int out_size, void* d_ws, size_t ws_size,
                              hipStream_t stream) {
    const float* x     = (const float*)d_in[0];
    const float* gamma = (const float*)d_in[1];
    const float* w1    = (const float*)d_in[2];
    const float* b1    = (const float*)d_in[3];
    const float* w2    = (const float*)d_in[4];
    const float* b2    = (const float*)d_in[5];
    float* out = (float*)d_out;

    float* energy = (float*)d_ws;                                // B*C*C = 4 MB
    float* pooled = energy + (size_t)BATCH * CDIM * CDIM;
    float* gate   = pooled + BATCH * CDIM;

    hipMemsetAsync(energy, 0, (size_t)BATCH * CDIM * CDIM * sizeof(float), stream);
    hipMemsetAsync(pooled, 0, (size_t)BATCH * CDIM * sizeof(float), stream);
    gram_kernel<<<dim3(SPLITS * 2, BATCH), 512, 0, stream>>>(x, energy, pooled);
    se_kernel<<<BATCH, 256, 0, stream>>>(pooled, w1, b1, w2, b2, gate);
    softmax_kernel<<<BATCH * CDIM, 256, 0, stream>>>(energy);
    out_kernel<<<dim3(HW / BN, BATCH), 1024, 0, stream>>>(energy, x, gate, gamma, out);
}

// Round 7
// 275.186 us; speedup vs baseline: 1.4704x; 1.4704x over previous
//
#include <hip/hip_runtime.h>
#include <math.h>

#define BATCH 16
#define CDIM 256
#define HW 9216
#define RDIM 32
#define SPLITS 16
#define KSLAB (HW / SPLITS)   /* 576 */
#define KCH 32                /* gram k-columns per chunk */
#define NCH (KSLAB / KCH)     /* 18, even */

#define BN 256                /* out_kernel n-tile */
#define BK 64                 /* out_kernel k-chunk */
#define BOFF 32768            /* ldsB byte offset inside shared block */

typedef __attribute__((ext_vector_type(8))) short short8;
typedef __attribute__((ext_vector_type(4))) short short4_t;
typedef __attribute__((ext_vector_type(4))) float f32x4;
typedef __attribute__((ext_vector_type(8))) _Float16 half8;

__device__ __forceinline__ unsigned short bf16_rne(float x) {
    union { float f; unsigned u; } a; a.f = x;
    return (unsigned short)((a.u + 0x7fffu + ((a.u >> 16) & 1u)) >> 16);
}
__device__ __forceinline__ unsigned pack2(float lo, float hi) {
    return (unsigned)bf16_rne(lo) | ((unsigned)bf16_rne(hi) << 16);
}

// Non-draining barrier: ds ops visible, global loads STAY IN FLIGHT.
__device__ __forceinline__ void lds_barrier() {
    asm volatile("s_waitcnt lgkmcnt(0)" ::: "memory");
    __builtin_amdgcn_s_barrier();
}

// gram fp16 tile [256 rows][32 k], row stride 64 B. Swizzle byte bits 4-5 with
// ((row>>1)^(row>>3))&3: frag reads (16 rows, same 16B col) and staging writes
// both <=2-way conflicts (free, m136). Returns _Float16 element index.
__device__ __forceinline__ int gswz16(int row, int k) {
    int byte = (row << 6) + (k << 1);
    byte ^= (((row >> 1) ^ (row >> 3)) & 3) << 4;
    return byte >> 1;
}
// out-kernel swizzle (unchanged, row stride 128 B)
__device__ __forceinline__ int bofs(int row, int k) {
    return (((row) << 7) | ((k) << 1)) ^ (((row ^ (row >> 2)) & 7) << 4);
}

// ---------------- K1: energy = v v^T (split-K, fp16 MFMA, depth-2 prefetch) ----
// grid (SPLITS, BATCH), 1024 thr = 16 waves (4x4), wave tile 64x64.
// Double-buffered LDS, ONE raw barrier per chunk, global loads issued 2 chunks
// ahead and never drained at barriers. Atomic fp32 epilogue.
__global__ __launch_bounds__(1024) void gram_kernel(const float* __restrict__ x,
                                                    float* __restrict__ energy,
                                                    float* __restrict__ pooled) {
    int split = blockIdx.x;
    int b     = blockIdx.y;
    const float* v = x + (size_t)b * CDIM * HW;
    int kbase0 = split * KSLAB;

    __shared__ _Float16 lds[2][CDIM * KCH];   // 2 x 16 KB

    int t    = threadIdx.x;
    int row  = t >> 2;          // staged channel row 0..255
    int kq   = t & 3;           // k-octet within chunk (8 floats)
    int lane = t & 63;
    int wave = t >> 6;
    int wr   = wave >> 2, wc = wave & 3;
    int lhi  = lane >> 4, llo = lane & 15;

    const float4* vrow = (const float4*)(v + (size_t)row * HW);

    f32x4 acc[4][4];
    #pragma unroll
    for (int i = 0; i < 4; ++i)
        #pragma unroll
        for (int j = 0; j < 4; ++j)
            acc[i][j] = (f32x4){0.f, 0.f, 0.f, 0.f};

    float psum = 0.f;
    float4 fa0, fa1, fb0, fb1;

    // prologue: load chunks 0 and 1
    {
        int kb0 = kbase0;
        fa0 = vrow[(kb0 >> 2) + kq * 2];
        fa1 = vrow[(kb0 >> 2) + kq * 2 + 1];
        int kb1 = kbase0 + KCH;
        fb0 = vrow[(kb1 >> 2) + kq * 2];
        fb1 = vrow[(kb1 >> 2) + kq * 2 + 1];
    }

    auto body = [&](float4& g0, float4& g1, _Float16* buf, int ch) {
        // convert (compiler emits counted vmcnt for g0/g1 here)
        float vals[8] = { g0.x, g0.y, g0.z, g0.w, g1.x, g1.y, g1.z, g1.w };
        half8 h;
        #pragma unroll
        for (int j = 0; j < 8; ++j) {
            psum += vals[j];
            h[j] = (_Float16)vals[j];
        }
        *(half8*)&buf[gswz16(row, kq * 8)] = h;
        // issue loads for chunk ch+2 (stay in flight across barriers)
        if (ch + 2 < NCH) {
            int kb = kbase0 + (ch + 2) * KCH;
            g0 = vrow[(kb >> 2) + kq * 2];
            g1 = vrow[(kb >> 2) + kq * 2 + 1];
        }
        lds_barrier();   // ds_writes visible; globals NOT drained

        half8 A[4], B[4];
        #pragma unroll
        for (int rb = 0; rb < 4; ++rb)
            A[rb] = *(const half8*)&buf[gswz16(wr * 64 + rb * 16 + llo, lhi * 8)];
        #pragma unroll
        for (int cb = 0; cb < 4; ++cb)
            B[cb] = *(const half8*)&buf[gswz16(wc * 64 + cb * 16 + llo, lhi * 8)];

        __builtin_amdgcn_s_setprio(1);
        #pragma unroll
        for (int rb = 0; rb < 4; ++rb)
            #pragma unroll
            for (int cb = 0; cb < 4; ++cb)
                acc[rb][cb] = __builtin_amdgcn_mfma_f32_16x16x32_f16(A[rb], B[cb], acc[rb][cb], 0, 0, 0);
        __builtin_amdgcn_s_setprio(0);
    };

    #pragma unroll 1
    for (int it = 0; it < NCH / 2; ++it) {
        body(fa0, fa1, (_Float16*)lds[0], it * 2);
        body(fb0, fb1, (_Float16*)lds[1], it * 2 + 1);
    }

    // pooled: 4 threads per row hold partials
    psum += __shfl_xor(psum, 1);
    psum += __shfl_xor(psum, 2);
    if (kq == 0) atomicAdd(&pooled[b * CDIM + row], psum);

    // energy atomic epilogue (C/D: col = lane&15, row = (lane>>4)*4 + reg)
    #pragma unroll
    for (int rb = 0; rb < 4; ++rb) {
        int r0 = wr * 64 + rb * 16 + lhi * 4;
        #pragma unroll
        for (int cb = 0; cb < 4; ++cb) {
            int c0 = wc * 64 + cb * 16 + llo;
            #pragma unroll
            for (int reg = 0; reg < 4; ++reg)
                atomicAdd(&energy[((size_t)b * CDIM + r0 + reg) * CDIM + c0], acc[rb][cb][reg]);
        }
    }
}

// ---------------- K2: SE MLP -> sigmoid gate ----------------
__global__ __launch_bounds__(256) void se_kernel(const float* __restrict__ pooled,
                                                 const float* __restrict__ w1,
                                                 const float* __restrict__ b1,
                                                 const float* __restrict__ w2,
                                                 const float* __restrict__ b2,
                                                 float* __restrict__ gate) {
    int b = blockIdx.x;
    int t = threadIdx.x;
    __shared__ float p[CDIM];
    __shared__ float hid[RDIM];
    p[t] = pooled[b * CDIM + t] * (1.0f / HW);
    __syncthreads();
    if (t < RDIM) {
        float s = b1[t];
        const float* wr = w1 + t * CDIM;
        for (int k = 0; k < CDIM; ++k) s = fmaf(wr[k], p[k], s);
        hid[t] = s > 0.f ? s : 0.f;
    }
    __syncthreads();
    float s = b2[t];
    const float* wr = w2 + t * RDIM;
    #pragma unroll
    for (int k = 0; k < RDIM; ++k) s = fmaf(wr[k], hid[k], s);
    gate[b * CDIM + t] = 1.0f / (1.0f + expf(-s));
}

// ---------------- K3: row softmax of (rowmax - energy), in place ----------------
__global__ __launch_bounds__(256) void softmax_kernel(float* __restrict__ energy) {
    int row = blockIdx.x;
    float* e = energy + (size_t)row * CDIM;
    int t = threadIdx.x;
    float val = e[t];

    float m = val;
    for (int off = 32; off > 0; off >>= 1) m = fminf(m, __shfl_down(m, off));
    __shared__ float redm[4];
    if ((t & 63) == 0) redm[t >> 6] = m;
    __syncthreads();
    float rowmin = fminf(fminf(redm[0], redm[1]), fminf(redm[2], redm[3]));

    float p = expf(rowmin - val);
    float s = p;
    for (int off = 32; off > 0; off >>= 1) s += __shfl_down(s, off);
    __shared__ float reds[4];
    if ((t & 63) == 0) reds[t >> 6] = s;
    __syncthreads();
    float tot = reds[0] + reds[1] + reds[2] + reds[3];
    e[t] = p / tot;
}

// ---------------- K4: out = gamma * gate * (att @ v) + x  (bf16 MFMA) ----------
__global__ __launch_bounds__(1024) void out_kernel(const float* __restrict__ att,
                                                   const float* __restrict__ x,
                                                   const float* __restrict__ gate,
                                                   const float* __restrict__ gammap,
                                                   float* __restrict__ out) {
    __shared__ __align__(16) char lds[65536];   // A: 32KB @0, B: 32KB @BOFF

    const int t    = threadIdx.x;
    const int lane = t & 63;
    const int wave = t >> 6;
    const int wr   = wave >> 2, wc = wave & 3;
    const int lhi  = lane >> 4, llo = lane & 15;
    const int nblk = blockIdx.x * BN;
    const int b    = blockIdx.y;

    const float* v    = x   + (size_t)b * CDIM * HW;
    const float* attb = att + (size_t)b * CDIM * CDIM;

    f32x4 acc[4][4];
    #pragma unroll
    for (int i = 0; i < 4; ++i)
        #pragma unroll
        for (int j = 0; j < 4; ++j)
            acc[i][j] = (f32x4){0.f, 0.f, 0.f, 0.f};

    float4 va0[2], va1[2], aa[4];

    auto load_chunk = [&](int k0) {
        #pragma unroll
        for (int i = 0; i < 2; ++i) {
            int dd0 = 2 * (wave + 16 * i);
            const float* r0 = v + (size_t)(k0 + dd0) * HW + nblk + lane * 4;
            va0[i] = *(const float4*)r0;
            va1[i] = *(const float4*)(r0 + HW);
        }
        #pragma unroll
        for (int i = 0; i < 4; ++i) {
            int c = (t >> 4) + 64 * i;
            aa[i] = *(const float4*)&attb[(size_t)c * CDIM + k0 + (t & 15) * 4];
        }
    };

    load_chunk(0);

    for (int ch = 0; ch < 4; ++ch) {
        __builtin_amdgcn_s_barrier();   // prior chunk's frag reads retired (consumed)
        #pragma unroll
        for (int i = 0; i < 2; ++i) {
            int dd0 = 2 * (wave + 16 * i);
            const float* f0 = (const float*)&va0[i];
            const float* f1 = (const float*)&va1[i];
            #pragma unroll
            for (int j = 0; j < 4; ++j) {
                int n = lane * 4 + j;
                *(unsigned*)(lds + BOFF + bofs(n, dd0)) = pack2(f0[j], f1[j]);
            }
        }
        #pragma unroll
        for (int i = 0; i < 4; ++i) {
            int c = (t >> 4) + 64 * i;
            const float* fa = (const float*)&aa[i];
            short4_t h = { (short)bf16_rne(fa[0]), (short)bf16_rne(fa[1]),
                           (short)bf16_rne(fa[2]), (short)bf16_rne(fa[3]) };
            *(short4_t*)(lds + bofs(c, (t & 15) * 4)) = h;
        }

        if (ch < 3) load_chunk((ch + 1) * BK);   // in flight across the barrier

        lds_barrier();   // writes visible; globals NOT drained

        #pragma unroll
        for (int ks = 0; ks < 2; ++ks) {
            int kb = ks * 32 + lhi * 8;
            short8 Af[4], Bf[4];
            #pragma unroll
            for (int rb = 0; rb < 4; ++rb)
                Af[rb] = *(const short8*)(lds + bofs(wr * 64 + rb * 16 + llo, kb));
            #pragma unroll
            for (int cb = 0; cb < 4; ++cb)
                Bf[cb] = *(const short8*)(lds + BOFF + bofs(wc * 64 + cb * 16 + llo, kb));
            __builtin_amdgcn_s_setprio(1);
            #pragma unroll
            for (int rb = 0; rb < 4; ++rb)
                #pragma unroll
                for (int cb = 0; cb < 4; ++cb)
                    acc[rb][cb] = __builtin_amdgcn_mfma_f32_16x16x32_bf16(Af[rb], Bf[cb], acc[rb][cb], 0, 0, 0);
            __builtin_amdgcn_s_setprio(0);
        }
    }

    float gm = gammap[0];
    #pragma unroll
    for (int rb = 0; rb < 4; ++rb) {
        #pragma unroll
        for (int r = 0; r < 4; ++r) {
            int c = wr * 64 + rb * 16 + lhi * 4 + r;
            float g = gm * gate[b * CDIM + c];
            size_t rowbase = ((size_t)b * CDIM + c) * HW + nblk;
            #pragma unroll
            for (int cb = 0; cb < 4; ++cb) {
                int n = wc * 64 + cb * 16 + llo;
                out[rowbase + n] = fmaf(acc[rb][cb][r], g, x[rowbase + n]);
            }
        }
    }
}

extern "C" void kernel_launch(void* const* d_in, const int* in_sizes, int n_in,
                              void* d_out, int out_size, void* d_ws, size_t ws_size,
                              hipStream_t stream) {
    const float* x     = (const float*)d_in[0];
    const float* gamma = (const float*)d_in[1];
    const float* w1    = (const float*)d_in[2];
    const float* b1    = (const float*)d_in[3];
    const float* w2    = (const float*)d_in[4];
    const float* b2    = (const float*)d_in[5];
    float* out = (float*)d_out;

    float* energy = (float*)d_ws;                                // B*C*C = 4 MB
    float* pooled = energy + (size_t)BATCH * CDIM * CDIM;
    float* gate   = pooled + BATCH * CDIM;

    hipMemsetAsync(energy, 0, (size_t)BATCH * CDIM * CDIM * sizeof(float), stream);
    hipMemsetAsync(pooled, 0, (size_t)BATCH * CDIM * sizeof(float), stream);
    gram_kernel<<<dim3(SPLITS, BATCH), 1024, 0, stream>>>(x, energy, pooled);
    se_kernel<<<BATCH, 256, 0, stream>>>(pooled, w1, b1, w2, b2, gate);
    softmax_kernel<<<BATCH * CDIM, 256, 0, stream>>>(energy);
    out_kernel<<<dim3(HW / BN, BATCH), 1024, 0, stream>>>(energy, x, gate, gamma, out);
}

// Round 8
// 234.222 us; speedup vs baseline: 1.7275x; 1.1749x over previous
//
#include <hip/hip_runtime.h>
#include <math.h>

#define BATCH 16
#define CDIM 256
#define HW 9216
#define RDIM 32
#define SPLITS 16
#define KSLAB (HW / SPLITS)   /* 576 */
#define KCH 32                /* gram k-columns per chunk */
#define NCH (KSLAB / KCH)     /* 18, even */

#define BN 256                /* out_kernel n-tile */
#define BK 64                 /* out_kernel k-chunk */
#define BOFF 32768            /* v^T tile byte offset inside shared block */

typedef __attribute__((ext_vector_type(8))) short short8;
typedef __attribute__((ext_vector_type(4))) short short4_t;
typedef __attribute__((ext_vector_type(4))) float f32x4;
typedef __attribute__((ext_vector_type(8))) _Float16 half8;

__device__ __forceinline__ unsigned short bf16_rne(float x) {
    union { float f; unsigned u; } a; a.f = x;
    return (unsigned short)((a.u + 0x7fffu + ((a.u >> 16) & 1u)) >> 16);
}
__device__ __forceinline__ unsigned pack2(float lo, float hi) {
    return (unsigned)bf16_rne(lo) | ((unsigned)bf16_rne(hi) << 16);
}

// Non-draining barrier: ds ops visible, global loads STAY IN FLIGHT (gram only).
__device__ __forceinline__ void lds_barrier() {
    asm volatile("s_waitcnt lgkmcnt(0)" ::: "memory");
    __builtin_amdgcn_s_barrier();
}

// gram fp16 tile [256 rows][32 k], row stride 64 B (2-way max conflicts).
__device__ __forceinline__ int gswz16(int row, int k) {
    int byte = (row << 6) + (k << 1);
    byte ^= (((row >> 1) ^ (row >> 3)) & 3) << 4;
    return byte >> 1;
}
// out-kernel swizzle (row stride 128 B)
__device__ __forceinline__ int bofs(int row, int k) {
    return (((row) << 7) | ((k) << 1)) ^ (((row ^ (row >> 2)) & 7) << 4);
}

// ---------------- K1: energy = v v^T (split-K, fp16 MFMA, depth-2 prefetch) ----
// (unchanged from R6 -- measured improvement)
__global__ __launch_bounds__(1024) void gram_kernel(const float* __restrict__ x,
                                                    float* __restrict__ energy,
                                                    float* __restrict__ pooled) {
    int split = blockIdx.x;
    int b     = blockIdx.y;
    const float* v = x + (size_t)b * CDIM * HW;
    int kbase0 = split * KSLAB;

    __shared__ _Float16 lds[2][CDIM * KCH];   // 2 x 16 KB

    int t    = threadIdx.x;
    int row  = t >> 2;
    int kq   = t & 3;
    int lane = t & 63;
    int wave = t >> 6;
    int wr   = wave >> 2, wc = wave & 3;
    int lhi  = lane >> 4, llo = lane & 15;

    const float4* vrow = (const float4*)(v + (size_t)row * HW);

    f32x4 acc[4][4];
    #pragma unroll
    for (int i = 0; i < 4; ++i)
        #pragma unroll
        for (int j = 0; j < 4; ++j)
            acc[i][j] = (f32x4){0.f, 0.f, 0.f, 0.f};

    float psum = 0.f;
    float4 fa0, fa1, fb0, fb1;

    {
        int kb0 = kbase0;
        fa0 = vrow[(kb0 >> 2) + kq * 2];
        fa1 = vrow[(kb0 >> 2) + kq * 2 + 1];
        int kb1 = kbase0 + KCH;
        fb0 = vrow[(kb1 >> 2) + kq * 2];
        fb1 = vrow[(kb1 >> 2) + kq * 2 + 1];
    }

    auto body = [&](float4& g0, float4& g1, _Float16* buf, int ch) {
        float vals[8] = { g0.x, g0.y, g0.z, g0.w, g1.x, g1.y, g1.z, g1.w };
        half8 h;
        #pragma unroll
        for (int j = 0; j < 8; ++j) {
            psum += vals[j];
            h[j] = (_Float16)vals[j];
        }
        *(half8*)&buf[gswz16(row, kq * 8)] = h;
        if (ch + 2 < NCH) {
            int kb = kbase0 + (ch + 2) * KCH;
            g0 = vrow[(kb >> 2) + kq * 2];
            g1 = vrow[(kb >> 2) + kq * 2 + 1];
        }
        lds_barrier();

        half8 A[4], B[4];
        #pragma unroll
        for (int rb = 0; rb < 4; ++rb)
            A[rb] = *(const half8*)&buf[gswz16(wr * 64 + rb * 16 + llo, lhi * 8)];
        #pragma unroll
        for (int cb = 0; cb < 4; ++cb)
            B[cb] = *(const half8*)&buf[gswz16(wc * 64 + cb * 16 + llo, lhi * 8)];

        __builtin_amdgcn_s_setprio(1);
        #pragma unroll
        for (int rb = 0; rb < 4; ++rb)
            #pragma unroll
            for (int cb = 0; cb < 4; ++cb)
                acc[rb][cb] = __builtin_amdgcn_mfma_f32_16x16x32_f16(A[rb], B[cb], acc[rb][cb], 0, 0, 0);
        __builtin_amdgcn_s_setprio(0);
    };

    #pragma unroll 1
    for (int it = 0; it < NCH / 2; ++it) {
        body(fa0, fa1, (_Float16*)lds[0], it * 2);
        body(fb0, fb1, (_Float16*)lds[1], it * 2 + 1);
    }

    psum += __shfl_xor(psum, 1);
    psum += __shfl_xor(psum, 2);
    if (kq == 0) atomicAdd(&pooled[b * CDIM + row], psum);

    #pragma unroll
    for (int rb = 0; rb < 4; ++rb) {
        int r0 = wr * 64 + rb * 16 + lhi * 4;
        #pragma unroll
        for (int cb = 0; cb < 4; ++cb) {
            int c0 = wc * 64 + cb * 16 + llo;
            #pragma unroll
            for (int reg = 0; reg < 4; ++reg)
                atomicAdd(&energy[((size_t)b * CDIM + r0 + reg) * CDIM + c0], acc[rb][cb][reg]);
        }
    }
}

// ---------------- K2: SE MLP -> sigmoid gate ----------------
__global__ __launch_bounds__(256) void se_kernel(const float* __restrict__ pooled,
                                                 const float* __restrict__ w1,
                                                 const float* __restrict__ b1,
                                                 const float* __restrict__ w2,
                                                 const float* __restrict__ b2,
                                                 float* __restrict__ gate) {
    int b = blockIdx.x;
    int t = threadIdx.x;
    __shared__ float p[CDIM];
    __shared__ float hid[RDIM];
    p[t] = pooled[b * CDIM + t] * (1.0f / HW);
    __syncthreads();
    if (t < RDIM) {
        float s = b1[t];
        const float* wr = w1 + t * CDIM;
        for (int k = 0; k < CDIM; ++k) s = fmaf(wr[k], p[k], s);
        hid[t] = s > 0.f ? s : 0.f;
    }
    __syncthreads();
    float s = b2[t];
    const float* wr = w2 + t * RDIM;
    #pragma unroll
    for (int k = 0; k < RDIM; ++k) s = fmaf(wr[k], hid[k], s);
    gate[b * CDIM + t] = 1.0f / (1.0f + expf(-s));
}

// ---------------- K3: row softmax of (rowmax - energy), in place ----------------
__global__ __launch_bounds__(256) void softmax_kernel(float* __restrict__ energy) {
    int row = blockIdx.x;
    float* e = energy + (size_t)row * CDIM;
    int t = threadIdx.x;
    float val = e[t];

    float m = val;
    for (int off = 32; off > 0; off >>= 1) m = fminf(m, __shfl_down(m, off));
    __shared__ float redm[4];
    if ((t & 63) == 0) redm[t >> 6] = m;
    __syncthreads();
    float rowmin = fminf(fminf(redm[0], redm[1]), fminf(redm[2], redm[3]));

    float p = expf(rowmin - val);
    float s = p;
    for (int off = 32; off > 0; off >>= 1) s += __shfl_down(s, off);
    __shared__ float reds[4];
    if ((t & 63) == 0) reds[t >> 6] = s;
    __syncthreads();
    float tot = reds[0] + reds[1] + reds[2] + reds[3];
    e[t] = p / tot;
}

// ---------------- K4: out = gamma * gate * (att @ v) + x  (bf16 MFMA) ----------
// OPERAND SWAP: D = A.B with A = v^T frags (rows = n), B = att frags (cols = c).
// C/D layout (col=lane&15, row=(lane>>4)*4+reg) then gives each lane 4
// consecutive n at fixed c -> float4 residual loads + float4 stores.
// Barriers: R5-proven __syncthreads schedule.
__global__ __launch_bounds__(1024) void out_kernel(const float* __restrict__ att,
                                                   const float* __restrict__ x,
                                                   const float* __restrict__ gate,
                                                   const float* __restrict__ gammap,
                                                   float* __restrict__ out) {
    __shared__ __align__(16) char lds[65536];   // att: 32KB @0, v^T: 32KB @BOFF

    const int t    = threadIdx.x;
    const int lane = t & 63;
    const int wave = t >> 6;
    const int wn   = wave >> 2;      // wave n-index (0..3)
    const int wcc  = wave & 3;       // wave c-index (0..3)
    const int lhi  = lane >> 4, llo = lane & 15;
    const int nblk = blockIdx.x * BN;
    const int b    = blockIdx.y;

    const float* v    = x   + (size_t)b * CDIM * HW;
    const float* attb = att + (size_t)b * CDIM * CDIM;

    f32x4 acc[4][4];   // [rb over n][cb over c]
    #pragma unroll
    for (int i = 0; i < 4; ++i)
        #pragma unroll
        for (int j = 0; j < 4; ++j)
            acc[i][j] = (f32x4){0.f, 0.f, 0.f, 0.f};

    float4 va0[2], va1[2], aa[4];

    auto load_chunk = [&](int k0) {
        #pragma unroll
        for (int i = 0; i < 2; ++i) {
            int dd0 = 2 * (wave + 16 * i);
            const float* r0 = v + (size_t)(k0 + dd0) * HW + nblk + lane * 4;
            va0[i] = *(const float4*)r0;
            va1[i] = *(const float4*)(r0 + HW);
        }
        #pragma unroll
        for (int i = 0; i < 4; ++i) {
            int c = (t >> 4) + 64 * i;
            aa[i] = *(const float4*)&attb[(size_t)c * CDIM + k0 + (t & 15) * 4];
        }
    };

    load_chunk(0);

    for (int ch = 0; ch < 4; ++ch) {
        __syncthreads();   // prior chunk's frag reads done
        #pragma unroll
        for (int i = 0; i < 2; ++i) {
            int dd0 = 2 * (wave + 16 * i);
            const float* f0 = (const float*)&va0[i];
            const float* f1 = (const float*)&va1[i];
            #pragma unroll
            for (int j = 0; j < 4; ++j) {
                int n = lane * 4 + j;
                *(unsigned*)(lds + BOFF + bofs(n, dd0)) = pack2(f0[j], f1[j]);
            }
        }
        #pragma unroll
        for (int i = 0; i < 4; ++i) {
            int c = (t >> 4) + 64 * i;
            const float* fa = (const float*)&aa[i];
            short4_t h = { (short)bf16_rne(fa[0]), (short)bf16_rne(fa[1]),
                           (short)bf16_rne(fa[2]), (short)bf16_rne(fa[3]) };
            *(short4_t*)(lds + bofs(c, (t & 15) * 4)) = h;
        }
        __syncthreads();   // tile staged

        if (ch < 3) load_chunk((ch + 1) * BK);   // prefetch under MFMA

        #pragma unroll
        for (int ks = 0; ks < 2; ++ks) {
            int kb = ks * 32 + lhi * 8;
            short8 An[4], Bc[4];
            #pragma unroll
            for (int rb = 0; rb < 4; ++rb)   // A = v^T rows (n)
                An[rb] = *(const short8*)(lds + BOFF + bofs(wn * 64 + rb * 16 + llo, kb));
            #pragma unroll
            for (int cb = 0; cb < 4; ++cb)   // B = att cols (c)
                Bc[cb] = *(const short8*)(lds + bofs(wcc * 64 + cb * 16 + llo, kb));
            #pragma unroll
            for (int rb = 0; rb < 4; ++rb)
                #pragma unroll
                for (int cb = 0; cb < 4; ++cb)
                    acc[rb][cb] = __builtin_amdgcn_mfma_f32_16x16x32_bf16(An[rb], Bc[cb], acc[rb][cb], 0, 0, 0);
        }
    }

    // ---- epilogue: per lane, col c fixed, 4 consecutive n -> float4 ----
    float gm = gammap[0];
    float gv[4];
    #pragma unroll
    for (int cb = 0; cb < 4; ++cb)
        gv[cb] = gm * gate[b * CDIM + wcc * 64 + cb * 16 + llo];

    #pragma unroll
    for (int rb = 0; rb < 4; ++rb) {
        int n0 = wn * 64 + rb * 16 + lhi * 4;
        #pragma unroll
        for (int cb = 0; cb < 4; ++cb) {
            int c = wcc * 64 + cb * 16 + llo;
            size_t base = ((size_t)b * CDIM + c) * HW + nblk + n0;
            float4 xv = *(const float4*)&x[base];
            float4 o;
            o.x = fmaf(acc[rb][cb][0], gv[cb], xv.x);
            o.y = fmaf(acc[rb][cb][1], gv[cb], xv.y);
            o.z = fmaf(acc[rb][cb][2], gv[cb], xv.z);
            o.w = fmaf(acc[rb][cb][3], gv[cb], xv.w);
            *(float4*)&out[base] = o;
        }
    }
}

extern "C" void kernel_launch(void* const* d_in, const int* in_sizes, int n_in,
                              void* d_out, int out_size, void* d_ws, size_t ws_size,
                              hipStream_t stream) {
    const float* x     = (const float*)d_in[0];
    const float* gamma = (const float*)d_in[1];
    const float* w1    = (const float*)d_in[2];
    const float* b1    = (const float*)d_in[3];
    const float* w2    = (const float*)d_in[4];
    const float* b2    = (const float*)d_in[5];
    float* out = (float*)d_out;

    float* energy = (float*)d_ws;                                // B*C*C = 4 MB
    float* pooled = energy + (size_t)BATCH * CDIM * CDIM;
    float* gate   = pooled + BATCH * CDIM;

    hipMemsetAsync(energy, 0, (size_t)BATCH * CDIM * CDIM * sizeof(float), stream);
    hipMemsetAsync(pooled, 0, (size_t)BATCH * CDIM * sizeof(float), stream);
    gram_kernel<<<dim3(SPLITS, BATCH), 1024, 0, stream>>>(x, energy, pooled);
    se_kernel<<<BATCH, 256, 0, stream>>>(pooled, w1, b1, w2, b2, gate);
    softmax_kernel<<<BATCH * CDIM, 256, 0, stream>>>(energy);
    out_kernel<<<dim3(HW / BN, BATCH), 1024, 0, stream>>>(energy, x, gate, gamma, out);
}